// Round 1
// baseline (10058.492 us; speedup 1.0000x reference)
//
#include <hip/hip_runtime.h>
#include <hip/hip_bf16.h>
#include <math.h>

// Problem constants
#define NB   128
#define LSEQ 512
#define EE   256
#define HH2  256
#define HHH  512        // 2*HH2
#define TT   9
#define START_TAG 7
#define STOP_TAG  8
#define NEGV -10000.0f

// LSTM kernel config: grid = NBT*NHS = 256 blocks, 256 threads
#define NBT 8           // batch tiles
#define BTL 16          // batches per tile
#define NHS 32          // hidden-slice blocks
#define HSU 8           // hidden units per block -> 32 gate rows
// Padded LDS row: 512 floats + 4 pad per 64 -> 544 floats = 136 float4; chunk stride 17 f4
#define ROW_F4   136
#define CHUNK_F4 17
#define INLDS_F4 (BTL * ROW_F4)              // 2176 f4 per direction
#define ZBUF_OFF (2 * INLDS_F4 * 16)         // 69632 bytes
#define LDS_BYTES (ZBUF_OFF + 2 * 32 * BTL * 4)  // 73728 bytes

// Workspace layout (bytes)
#define X_BYTES   ((size_t)LSEQ * NB * EE * 4)         // 67,108,864
#define H_BYTES   ((size_t)LSEQ * NB * HHH * 4)        // 134,217,728
#define F_BYTES   ((size_t)LSEQ * NB * TT * 4)         // 2,359,296
#define FLAG_UINTS 1024                                 // 2 dirs * 8 groups * 64-uint spacing

// ---------------------------------------------------------------- embed
__global__ void embed_kernel(const int* __restrict__ tokens,
                             const float* __restrict__ emb,
                             float* __restrict__ x) {
  int g = blockIdx.x * blockDim.x + threadIdx.x;  // one float4 each
  int row = g >> 6;        // (l*128+b), 64 quads per row
  int q   = g & 63;
  int l = row >> 7, b = row & 127;
  int tok = tokens[b * LSEQ + l];
  float4 v = *(const float4*)(emb + (size_t)tok * EE + q * 4);
  *(float4*)(x + (size_t)row * EE + q * 4) = v;
}

// ---------------------------------------------------------------- flags init
__global__ void init_kernel(unsigned int* flags) {
  int i = threadIdx.x;
  for (; i < FLAG_UINTS; i += 256) flags[i] = 0u;
}

// ---------------------------------------------------------------- LSTM (persistent, both dirs)
__global__ __launch_bounds__(256, 1)
void lstm_kernel(const float* __restrict__ x,
                 const float* __restrict__ Wih_f, const float* __restrict__ Whh_f,
                 const float* __restrict__ bih_f, const float* __restrict__ bhh_f,
                 const float* __restrict__ Wih_b, const float* __restrict__ Whh_b,
                 const float* __restrict__ bih_b, const float* __restrict__ bhh_b,
                 const float* __restrict__ h0, const float* __restrict__ c0,
                 float* __restrict__ h_out, unsigned int* __restrict__ flags) {
  extern __shared__ char smem[];
  float4* in4  = (float4*)smem;                  // [2][BTL][ROW_F4]
  float*  zbuf = (float*)(smem + ZBUF_OFF);      // [2][32][BTL]

  const int tid = threadIdx.x;
  const int bt  = blockIdx.x >> 5;   // batch tile 0..7
  const int hs  = blockIdx.x & 31;   // hidden slice 0..31

  // ---- weights into registers: thread (r, kc); r = gate*8+ul (32 rows), kc = k-chunk of 64
  const int r  = tid >> 3, kc = tid & 7;
  const int gate = r >> 3, ul = r & 7;
  const int grow = gate * 256 + hs * HSU + ul;
  float4 wf[16], wb[16];
#pragma unroll
  for (int j4 = 0; j4 < 16; ++j4) {
    int k = kc * 64 + j4 * 4;
    const float* pf = (k < 256) ? (Wih_f + (size_t)grow * 256 + k)
                                : (Whh_f + (size_t)grow * 256 + (k - 256));
    const float* pb = (k < 256) ? (Wih_b + (size_t)grow * 256 + k)
                                : (Whh_b + (size_t)grow * 256 + (k - 256));
    wf[j4] = *(const float4*)pf;
    wb[j4] = *(const float4*)pb;
  }

  // ---- updater state (threads 0..127): b = tid&15, u = (tid>>4)&7
  const int ub = tid & 15, uu = (tid >> 4) & 7;
  const int bglob_u = bt * BTL + ub, uglob_u = hs * HSU + uu;
  float cF = 0.f, cB = 0.f;
  float biasF[4], biasB[4];
  if (tid < 128) {
    cF = c0[(size_t)0 * NB * HH2 + (size_t)bglob_u * HH2 + uglob_u];
    cB = c0[(size_t)1 * NB * HH2 + (size_t)bglob_u * HH2 + uglob_u];
#pragma unroll
    for (int g2 = 0; g2 < 4; ++g2) {
      int gr = g2 * 256 + uglob_u;
      biasF[g2] = bih_f[gr] + bhh_f[gr];
      biasB[g2] = bih_b[gr] + bhh_b[gr];
    }
  }

  unsigned int* flagF = flags + bt * 64;
  unsigned int* flagB = flags + 512 + bt * 64;

  // stage inputs for direction d at source time tt (step t) into in4[d]
  auto stage = [&](int d, int tt, int t) {
#pragma unroll
    for (int c = 0; c < 8; ++c) {
      int fid = c * 256 + tid;     // 0..2047 float4 slots
      int b   = fid >> 7;          // 0..15
      int q   = fid & 127;         // f4 index in 512-float logical row
      int k   = q * 4;
      int bg  = bt * BTL + b;
      float4 v;
      if (k < 256) {
        v = *(const float4*)(x + ((size_t)tt * NB + bg) * EE + k);
      } else {
        int ko = k - 256;
        if (t == 0) {
          v = *(const float4*)(h0 + ((size_t)d * NB + bg) * HH2 + ko);
        } else {
          int tprev = (d == 0) ? (t - 1) : (LSEQ - t);
          v = *(const float4*)(h_out + ((size_t)tprev * NB + bg) * HHH + d * HH2 + ko);
        }
      }
      in4[d * INLDS_F4 + b * ROW_F4 + (q >> 4) * CHUNK_F4 + (q & 15)] = v;
    }
  };

  auto compute = [&](int d, const float4 (&w)[16]) {
    const float4* base = in4 + d * INLDS_F4 + kc * CHUNK_F4;
#pragma unroll 2
    for (int b = 0; b < BTL; ++b) {
      const float4* p = base + b * ROW_F4;
      float ax = 0.f, ay = 0.f, az = 0.f, aw2 = 0.f;
#pragma unroll
      for (int j4 = 0; j4 < 16; ++j4) {
        float4 v = p[j4];
        ax  = fmaf(w[j4].x, v.x, ax);
        ay  = fmaf(w[j4].y, v.y, ay);
        az  = fmaf(w[j4].z, v.z, az);
        aw2 = fmaf(w[j4].w, v.w, aw2);
      }
      float s = (ax + ay) + (az + aw2);
      s += __shfl_xor(s, 1);
      s += __shfl_xor(s, 2);
      s += __shfl_xor(s, 4);
      if (kc == (b & 7)) zbuf[(d * 32 + r) * BTL + b] = s;
    }
  };

  auto update = [&](int d, float& cc, const float* bias, int t) {
    if (tid < 128) {
      float zi = zbuf[(d * 32 + 0 * 8 + uu) * BTL + ub] + bias[0];
      float zf = zbuf[(d * 32 + 1 * 8 + uu) * BTL + ub] + bias[1];
      float zg = zbuf[(d * 32 + 2 * 8 + uu) * BTL + ub] + bias[2];
      float zo = zbuf[(d * 32 + 3 * 8 + uu) * BTL + ub] + bias[3];
      float ig = 1.f / (1.f + __expf(-zi));
      float fg = 1.f / (1.f + __expf(-zf));
      float gg = tanhf(zg);
      float og = 1.f / (1.f + __expf(-zo));
      cc = fg * cc + ig * gg;
      float hv = og * tanhf(cc);
      int tt = (d == 0) ? t : (LSEQ - 1 - t);
      // sc1 store: bypass this XCD's L2 so other groups' blocks see it via L3
      __hip_atomic_store(h_out + ((size_t)tt * NB + bglob_u) * HHH + d * HH2 + uglob_u,
                         hv, __ATOMIC_RELAXED, __HIP_MEMORY_SCOPE_AGENT);
      asm volatile("s_waitcnt vmcnt(0)" ::: "memory");  // my stores at L3 before flag
    }
  };

  auto wait_flag = [&](unsigned int* f, unsigned int target) {
    if (tid == 0) {
      while (__hip_atomic_load(f, __ATOMIC_RELAXED, __HIP_MEMORY_SCOPE_AGENT) < target) {
        __builtin_amdgcn_s_sleep(2);
      }
    }
    __syncthreads();
  };

  for (int t = 0; t < LSEQ; ++t) {
    // ---------- forward phase
    if (t > 0) wait_flag(flagF, 32u * (unsigned)t);
    stage(0, t, t);
    __syncthreads();
    compute(0, wf);
    __syncthreads();
    update(0, cF, biasF, t);
    __syncthreads();
    if (tid == 0)
      __hip_atomic_fetch_add(flagF, 1u, __ATOMIC_RELAXED, __HIP_MEMORY_SCOPE_AGENT);
    // ---------- backward phase (hides forward flag latency)
    if (t > 0) wait_flag(flagB, 32u * (unsigned)t);
    stage(1, LSEQ - 1 - t, t);
    __syncthreads();
    compute(1, wb);
    __syncthreads();
    update(1, cB, biasB, t);
    __syncthreads();
    if (tid == 0)
      __hip_atomic_fetch_add(flagB, 1u, __ATOMIC_RELAXED, __HIP_MEMORY_SCOPE_AGENT);
  }
}

// ---------------------------------------------------------------- feats: one wave per (l,b)
__global__ __launch_bounds__(64)
void feats_kernel(const float* __restrict__ h_out,
                  const float* __restrict__ W_out, const float* __restrict__ b_out,
                  float* __restrict__ feats) {
  int wid  = blockIdx.x;        // l*128 + b
  int lane = threadIdx.x;
  const float* hrow = h_out + (size_t)wid * HHH + lane * 8;
  float4 hv0 = *(const float4*)(hrow);
  float4 hv1 = *(const float4*)(hrow + 4);
  float res = 0.f;
#pragma unroll
  for (int tg = 0; tg < TT; ++tg) {
    const float* wrow = W_out + (size_t)tg * HHH + lane * 8;
    float4 w0 = *(const float4*)(wrow);
    float4 w1 = *(const float4*)(wrow + 4);
    float s = hv0.x * w0.x + hv0.y * w0.y + hv0.z * w0.z + hv0.w * w0.w
            + hv1.x * w1.x + hv1.y * w1.y + hv1.z * w1.z + hv1.w * w1.w;
#pragma unroll
    for (int off = 32; off >= 1; off >>= 1) s += __shfl_xor(s, off);
    if (lane == tg) res = s + b_out[tg];
  }
  if (lane < TT) feats[(size_t)wid * TT + lane] = res;
}

// ---------------------------------------------------------------- viterbi: one wave per batch
__global__ __launch_bounds__(64)
void viterbi_kernel(const float* __restrict__ feats, const float* __restrict__ trans,
                    float* __restrict__ out) {
  __shared__ float tr[TT * TT];
  __shared__ float abuf[2][16];
  __shared__ int   bptr[LSEQ][TT];
  __shared__ float finbuf[16];
  int b = blockIdx.x, lane = threadIdx.x;
  for (int i = lane; i < TT * TT; i += 64) tr[i] = trans[i];
  if (lane < 16) abuf[0][lane] = NEGV;
  __syncthreads();
  if (lane == START_TAG) abuf[0][lane] = 0.f;
  int cur = 0;
  for (int l = 0; l < LSEQ; ++l) {
    float feat = (lane < TT) ? feats[((size_t)l * NB + b) * TT + lane] : 0.f;
    if (lane < TT) {
      float best = -3.4e38f; int bp = 0;
#pragma unroll
      for (int p = 0; p < TT; ++p) {
        float s2 = abuf[cur][p] + tr[lane * TT + p];   // trans[nxt,prev]
        if (s2 > best) { best = s2; bp = p; }          // first-max, matches jnp.argmax
      }
      abuf[cur ^ 1][lane] = best + feat;
      bptr[l][lane] = bp;
    }
    cur ^= 1;
  }
  if (lane < 16) finbuf[lane] = -3.4e38f;
  if (lane < TT) finbuf[lane] = abuf[cur][lane] + tr[STOP_TAG * TT + lane];
  if (lane == 0) {
    float bestv = finbuf[0]; int btag = 0;
    for (int p = 1; p < TT; ++p) if (finbuf[p] > bestv) { bestv = finbuf[p]; btag = p; }
    out[b] = bestv;
    float* pathp = out + NB + (size_t)b * LSEQ;  // path written as float32
    int tag = btag;
    pathp[LSEQ - 1] = (float)tag;
    for (int l = LSEQ - 1; l >= 1; --l) {
      tag = bptr[l][tag];
      pathp[l - 1] = (float)tag;
    }
  }
}

// ---------------------------------------------------------------- launch
extern "C" void kernel_launch(void* const* d_in, const int* in_sizes, int n_in,
                              void* d_out, int out_size, void* d_ws, size_t ws_size,
                              hipStream_t stream) {
  const int*   tokens = (const int*)d_in[0];
  const float* emb    = (const float*)d_in[1];
  const float* Wih_f  = (const float*)d_in[2];
  const float* Whh_f  = (const float*)d_in[3];
  const float* bih_f  = (const float*)d_in[4];
  const float* bhh_f  = (const float*)d_in[5];
  const float* Wih_b  = (const float*)d_in[6];
  const float* Whh_b  = (const float*)d_in[7];
  const float* bih_b  = (const float*)d_in[8];
  const float* bhh_b  = (const float*)d_in[9];
  const float* W_out  = (const float*)d_in[10];
  const float* b_out  = (const float*)d_in[11];
  const float* trans  = (const float*)d_in[12];
  const float* h0     = (const float*)d_in[13];
  const float* c0     = (const float*)d_in[14];
  float* out = (float*)d_out;

  char* ws = (char*)d_ws;
  float* x     = (float*)ws;
  float* h_out = (float*)(ws + X_BYTES);
  float* feats = (float*)(ws + X_BYTES + H_BYTES);
  unsigned int* flags = (unsigned int*)(ws + X_BYTES + H_BYTES + F_BYTES);

  hipFuncSetAttribute((const void*)lstm_kernel,
                      hipFuncAttributeMaxDynamicSharedMemorySize, LDS_BYTES);

  init_kernel<<<1, 256, 0, stream>>>(flags);
  embed_kernel<<<(NB * LSEQ * EE / 4) / 256, 256, 0, stream>>>(tokens, emb, x);
  lstm_kernel<<<NBT * NHS, 256, LDS_BYTES, stream>>>(x, Wih_f, Whh_f, bih_f, bhh_f,
                                                     Wih_b, Whh_b, bih_b, bhh_b,
                                                     h0, c0, h_out, flags);
  feats_kernel<<<LSEQ * NB, 64, 0, stream>>>(h_out, W_out, b_out, feats);
  viterbi_kernel<<<NB, 64, 0, stream>>>(feats, trans, out);
}

// Round 2
// 2575.256 us; speedup vs baseline: 3.9058x; 3.9058x over previous
//
#include <hip/hip_runtime.h>
#include <hip/hip_bf16.h>
#include <math.h>

// Problem constants
#define NB   128
#define LSEQ 512
#define EE   256
#define HH2  256
#define HHH  512
#define TT   9
#define START_TAG 7
#define STOP_TAG  8
#define NEGV -10000.0f

// LSTM config: grid = 2 dirs * 4 batch-tiles * 8 unit-tiles = 64 blocks, 256 thr (4 waves = 4 gates)
// A-tile = [32 batch x 512 K] bf16 in MFMA fragment order: word(ks,lane) = A[b=lane&31][k=ks*16+(lane>>5)*8+e]
// LDS: Abuf[2 buf][32 ks][64 lanes][16B] = 64KB ; zbuf[4][32][34] f32 = 17408B
#define ABUF_BYTES 65536
#define ZROW 34
#define LDS_BYTES (ABUF_BYTES + 4 * 32 * ZROW * 4)

// Workspace layout (bytes)
#define XFRAG_BYTES  ((size_t)LSEQ * 4 * 16 * 64 * 16)        // 33,554,432
#define HFRAG_BYTES  ((size_t)LSEQ * 2 * 4 * 16 * 64 * 16)    // 67,108,864
#define HPLAIN_BYTES ((size_t)LSEQ * NB * HHH * 2)            // 67,108,864 (bf16)
#define FEATS_BYTES  ((size_t)LSEQ * NB * TT * 4)             // 2,359,296
#define OFF_HFRAG  XFRAG_BYTES
#define OFF_HPLAIN (OFF_HFRAG + HFRAG_BYTES)
#define OFF_FEATS  (OFF_HPLAIN + HPLAIN_BYTES)
#define OFF_FLAGS  (OFF_FEATS + FEATS_BYTES)

typedef float f32x16 __attribute__((ext_vector_type(16)));
typedef short short8 __attribute__((ext_vector_type(8)));

static __device__ __forceinline__ unsigned short f2bf(float f) {
  unsigned int u = __float_as_uint(f);
  unsigned int r = (u + 0x7fffu + ((u >> 16) & 1u)) >> 16;   // RNE
  return (unsigned short)r;
}
static __device__ __forceinline__ float bf2f(unsigned short s) {
  return __uint_as_float(((unsigned int)s) << 16);
}
static __device__ __forceinline__ float sigmoidf_(float x) {
  return 1.0f / (1.0f + __expf(-x));
}
static __device__ __forceinline__ float tanhf_(float x) {
  return 2.0f / (1.0f + __expf(-2.0f * x)) - 1.0f;
}

// ---------------------------------------------------------------- flags init
__global__ void init_kernel(unsigned int* flags) {
  if (threadIdx.x < 64) flags[threadIdx.x] = 0u;
}

// ---------------------------------------------------------------- embed -> x_frag (fragment order, bf16)
// word id = ((t*4+bt)*16+ks)*64 + l ; holds x[b=bt*32+(l&31)][k=ks*16+(l>>5)*8 + 0..7]
__global__ void embed_kernel(const int* __restrict__ tokens,
                             const float* __restrict__ emb,
                             uint4* __restrict__ x_frag) {
  int wid = blockIdx.x * blockDim.x + threadIdx.x;  // 0 .. 512*4*16*64-1
  int l  = wid & 63;
  int ks = (wid >> 6) & 15;
  int bt = (wid >> 10) & 3;
  int t  = wid >> 12;
  int b  = bt * 32 + (l & 31);
  int k  = ks * 16 + (l >> 5) * 8;
  int tok = tokens[b * LSEQ + t];
  const float* p = emb + (size_t)tok * EE + k;
  float4 v0 = *(const float4*)p;
  float4 v1 = *(const float4*)(p + 4);
  uint4 o;
  o.x = f2bf(v0.x) | ((unsigned)f2bf(v0.y) << 16);
  o.y = f2bf(v0.z) | ((unsigned)f2bf(v0.w) << 16);
  o.z = f2bf(v1.x) | ((unsigned)f2bf(v1.y) << 16);
  o.w = f2bf(v1.z) | ((unsigned)f2bf(v1.w) << 16);
  x_frag[wid] = o;
}

// ---------------------------------------------------------------- LSTM persistent MFMA kernel
__global__ __launch_bounds__(256, 1)
void lstm_kernel(const uint4* __restrict__ x_frag,
                 const float* __restrict__ Wih_f, const float* __restrict__ Whh_f,
                 const float* __restrict__ bih_f, const float* __restrict__ bhh_f,
                 const float* __restrict__ Wih_b, const float* __restrict__ Whh_b,
                 const float* __restrict__ bih_b, const float* __restrict__ bhh_b,
                 const float* __restrict__ h0, const float* __restrict__ c0,
                 uint4* __restrict__ h_frag, ushort* __restrict__ h_plain,
                 unsigned int* __restrict__ flags) {
  extern __shared__ char smem[];
  char*  abuf = smem;
  float* zbuf = (float*)(smem + ABUF_BYTES);

  const int tid  = threadIdx.x;
  const int wv   = tid >> 6;      // wave = gate type 0..3 (i,f,g,o)
  const int lane = tid & 63;
  const int d  = blockIdx.x >> 5;
  const int bt = (blockIdx.x >> 3) & 3;
  const int ut = blockIdx.x & 7;
  const int grp = d * 4 + bt;

  const float* Wih = d ? Wih_b : Wih_f;
  const float* Whh = d ? Whh_b : Whh_f;
  const float* bih = d ? bih_b : bih_f;
  const float* bhh = d ? bhh_b : bhh_f;

  // ---- weights -> B-fragments in VGPRs. B col = lane&31 (unit), k = ks*16+(lane>>5)*8+e
  short8 w[32];
  {
    int wrow = wv * 256 + ut * 32 + (lane & 31);
#pragma unroll
    for (int ks = 0; ks < 32; ++ks) {
      int k0 = ks * 16 + (lane >> 5) * 8;
      const float* src = (k0 < 256) ? (Wih + (size_t)wrow * 256 + k0)
                                    : (Whh + (size_t)wrow * 256 + (k0 - 256));
      float4 v0 = *(const float4*)src;
      float4 v1 = *(const float4*)(src + 4);
      short8 s;
      s[0] = (short)f2bf(v0.x); s[1] = (short)f2bf(v0.y);
      s[2] = (short)f2bf(v0.z); s[3] = (short)f2bf(v0.w);
      s[4] = (short)f2bf(v1.x); s[5] = (short)f2bf(v1.y);
      s[6] = (short)f2bf(v1.z); s[7] = (short)f2bf(v1.w);
      w[ks] = s;
    }
  }

  // ---- update-thread state (tid<128): j = tid>>6, l = tid&63 ; b = l&31, u0 = ut*32+16j+8*(l>>5)
  const int uj = tid >> 6;            // 0/1 valid when tid<128
  const int ul = tid & 63;
  const int ubl = ul & 31;
  const int u0l = 16 * uj + 8 * (ul >> 5);       // unit offset within tile (0..31)
  const int bg  = bt * 32 + ubl;                  // global batch
  const int ug  = ut * 32 + u0l;                  // global unit base
  float creg[8];
  float bias[4][8];
  if (tid < 128) {
    const float* cp = c0 + ((size_t)d * NB + bg) * HH2 + ug;
    float4 cv0 = *(const float4*)cp;
    float4 cv1 = *(const float4*)(cp + 4);
    creg[0]=cv0.x; creg[1]=cv0.y; creg[2]=cv0.z; creg[3]=cv0.w;
    creg[4]=cv1.x; creg[5]=cv1.y; creg[6]=cv1.z; creg[7]=cv1.w;
#pragma unroll
    for (int g = 0; g < 4; ++g) {
      int gr = g * 256 + ug;
      float4 a0 = *(const float4*)(bih + gr);
      float4 a1 = *(const float4*)(bih + gr + 4);
      float4 b0 = *(const float4*)(bhh + gr);
      float4 b1 = *(const float4*)(bhh + gr + 4);
      bias[g][0]=a0.x+b0.x; bias[g][1]=a0.y+b0.y; bias[g][2]=a0.z+b0.z; bias[g][3]=a0.w+b0.w;
      bias[g][4]=a1.x+b1.x; bias[g][5]=a1.y+b1.y; bias[g][6]=a1.z+b1.z; bias[g][7]=a1.w+b1.w;
    }
  }

  // ---- staging helpers (global_load_lds dwordx4: LDS dest = uniform base + lane*16)
  auto stage_x = [&](int tsrc) {
#pragma unroll
    for (int i = 0; i < 4; ++i) {
      int ks = wv * 4 + i;
      const char* gp = (const char*)x_frag +
          ((((size_t)tsrc * 4 + bt) * 16 + ks) * 64 + lane) * 16;
      char* lp = abuf + (((tsrc & 1) * 32 + ks) * 1024);
      __builtin_amdgcn_global_load_lds(
          (const __attribute__((address_space(1))) unsigned int*)gp,
          (__attribute__((address_space(3))) unsigned int*)lp, 16, 0, 0);
    }
  };
  auto stage_h = [&](int tsrc, int buf) {   // h_frag[tsrc] -> Abuf[buf] ks 16..31
#pragma unroll
    for (int i = 0; i < 4; ++i) {
      int ks2 = wv * 4 + i;
      const char* gp = (const char*)h_frag +
          (((((size_t)tsrc * 2 + d) * 4 + bt) * 16 + ks2) * 64 + lane) * 16;
      char* lp = abuf + ((buf * 32 + 16 + ks2) * 1024);
      __builtin_amdgcn_global_load_lds(
          (const __attribute__((address_space(1))) unsigned int*)gp,
          (__attribute__((address_space(3))) unsigned int*)lp, 16, 0, 0);
    }
  };

  // ---- prologue: x[0] via DMA; h0 (fp32 global) manually into buf0 ks16-31
  stage_x(0);
#pragma unroll
  for (int w2 = 0; w2 < 4; ++w2) {
    int wid = w2 * 256 + tid;       // 0..1023
    int ks2 = wid >> 6;             // 0..15
    int l2  = wid & 63;
    int u   = ks2 * 16 + (l2 >> 5) * 8;
    int b2  = bt * 32 + (l2 & 31);
    const float* p = h0 + ((size_t)d * NB + b2) * HH2 + u;
    float4 v0 = *(const float4*)p;
    float4 v1 = *(const float4*)(p + 4);
    uint4 o;
    o.x = f2bf(v0.x) | ((unsigned)f2bf(v0.y) << 16);
    o.y = f2bf(v0.z) | ((unsigned)f2bf(v0.w) << 16);
    o.z = f2bf(v1.x) | ((unsigned)f2bf(v1.y) << 16);
    o.w = f2bf(v1.z) | ((unsigned)f2bf(v1.w) << 16);
    *(uint4*)(abuf + ((16 + ks2) * 1024) + l2 * 16) = o;
  }
  asm volatile("s_waitcnt vmcnt(0)" ::: "memory");
  __syncthreads();

  // ---- main loop
  for (int t = 0; t < LSEQ; ++t) {
    const int cur = t & 1;
    if (t + 1 < LSEQ) stage_x(t + 1);
    if (t > 0) {
      // spin until all 8 producer blocks of this (d,bt) group posted step t
      const unsigned int tgt = (unsigned int)t;
      while (true) {
        unsigned int v = __hip_atomic_load(&flags[grp * 8 + (tid & 7)],
                                           __ATOMIC_RELAXED, __HIP_MEMORY_SCOPE_AGENT);
        if (__all(v >= tgt)) break;
        __builtin_amdgcn_s_sleep(1);
      }
      stage_h(t - 1, cur);
    }

    f32x16 acc0, acc1;
#pragma unroll
    for (int i = 0; i < 16; ++i) { acc0[i] = 0.0f; acc1[i] = 0.0f; }

    // x-half MFMAs (ks 0..15) — overlaps the h-load latency
#pragma unroll
    for (int ks = 0; ks < 16; ks += 2) {
      short8 a0 = *(const short8*)(abuf + ((cur * 32 + ks) * 1024) + lane * 16);
      short8 a1 = *(const short8*)(abuf + ((cur * 32 + ks + 1) * 1024) + lane * 16);
      asm volatile("v_mfma_f32_32x32x16_bf16 %0, %1, %2, %0"
                   : "+v"(acc0) : "v"(a0), "v"(w[ks]));
      asm volatile("v_mfma_f32_32x32x16_bf16 %0, %1, %2, %0"
                   : "+v"(acc1) : "v"(a1), "v"(w[ks + 1]));
    }
    asm volatile("s_waitcnt vmcnt(0)" ::: "memory");  // h (and x[t+1]) staged
    __syncthreads();
    // h-half MFMAs (ks 16..31)
#pragma unroll
    for (int ks = 16; ks < 32; ks += 2) {
      short8 a0 = *(const short8*)(abuf + ((cur * 32 + ks) * 1024) + lane * 16);
      short8 a1 = *(const short8*)(abuf + ((cur * 32 + ks + 1) * 1024) + lane * 16);
      asm volatile("v_mfma_f32_32x32x16_bf16 %0, %1, %2, %0"
                   : "+v"(acc0) : "v"(a0), "v"(w[ks]));
      asm volatile("v_mfma_f32_32x32x16_bf16 %0, %1, %2, %0"
                   : "+v"(acc1) : "v"(a1), "v"(w[ks + 1]));
    }
#pragma unroll
    for (int i = 0; i < 16; ++i) acc0[i] += acc1[i];

    // D layout (verified): col(unit) = lane&31, row(batch) = (r&3)+8*(r>>2)+4*(lane>>5)
#pragma unroll
    for (int r = 0; r < 16; ++r) {
      int brow = (r & 3) + 8 * (r >> 2) + 4 * (lane >> 5);
      zbuf[(wv * 32 + brow) * ZROW + (lane & 31)] = acc0[r];
    }
    __syncthreads();

    if (tid < 128) {
      float zr[4][8];
#pragma unroll
      for (int g = 0; g < 4; ++g) {
        const float* zp = zbuf + (g * 32 + ubl) * ZROW + u0l;
        float2 p0 = *(const float2*)zp;
        float2 p1 = *(const float2*)(zp + 2);
        float2 p2 = *(const float2*)(zp + 4);
        float2 p3 = *(const float2*)(zp + 6);
        zr[g][0]=p0.x; zr[g][1]=p0.y; zr[g][2]=p1.x; zr[g][3]=p1.y;
        zr[g][4]=p2.x; zr[g][5]=p2.y; zr[g][6]=p3.x; zr[g][7]=p3.y;
      }
      unsigned short hb[8];
#pragma unroll
      for (int e = 0; e < 8; ++e) {
        float ig = sigmoidf_(zr[0][e] + bias[0][e]);
        float fg = sigmoidf_(zr[1][e] + bias[1][e]);
        float gg = tanhf_   (zr[2][e] + bias[2][e]);
        float og = sigmoidf_(zr[3][e] + bias[3][e]);
        float c = fg * creg[e] + ig * gg;
        creg[e] = c;
        hb[e] = f2bf(og * tanhf_(c));
      }
      int tt = d ? (LSEQ - 1 - t) : t;
      // h_frag (fragment order) — agent-scope so other blocks see it via L3
      size_t fo = ((((size_t)tt * 2 + d) * 4 + bt) * 16 + (2 * ut + uj)) * 64 + ul;
      unsigned long long w0 = (unsigned long long)(hb[0] | ((unsigned)hb[1] << 16)) |
                              ((unsigned long long)(hb[2] | ((unsigned)hb[3] << 16)) << 32);
      unsigned long long w1 = (unsigned long long)(hb[4] | ((unsigned)hb[5] << 16)) |
                              ((unsigned long long)(hb[6] | ((unsigned)hb[7] << 16)) << 32);
      unsigned long long* fp = (unsigned long long*)((char*)h_frag + fo * 16);
      __hip_atomic_store(fp,     w0, __ATOMIC_RELAXED, __HIP_MEMORY_SCOPE_AGENT);
      __hip_atomic_store(fp + 1, w1, __ATOMIC_RELAXED, __HIP_MEMORY_SCOPE_AGENT);
      // h_plain [t][b][d*256+u] bf16 (consumed by feats after kernel end — plain store ok)
      uint4 hp;
      hp.x = hb[0] | ((unsigned)hb[1] << 16);
      hp.y = hb[2] | ((unsigned)hb[3] << 16);
      hp.z = hb[4] | ((unsigned)hb[5] << 16);
      hp.w = hb[6] | ((unsigned)hb[7] << 16);
      *(uint4*)(h_plain + (((size_t)tt * NB + bg) * HHH) + d * HH2 + ug) = hp;
    }
    asm volatile("s_waitcnt vmcnt(0)" ::: "memory");  // h stores drained
    __syncthreads();
    if (tid == 0)
      __hip_atomic_store(&flags[grp * 8 + ut], (unsigned int)(t + 1),
                         __ATOMIC_RELAXED, __HIP_MEMORY_SCOPE_AGENT);
  }
}

// ---------------------------------------------------------------- feats: 4 waves/block, one (t,b) row per wave
__global__ __launch_bounds__(256)
void feats_kernel(const ushort* __restrict__ h_plain,
                  const float* __restrict__ W_out, const float* __restrict__ b_out,
                  float* __restrict__ feats) {
  int wv = threadIdx.x >> 6, lane = threadIdx.x & 63;
  int wid = blockIdx.x * 4 + wv;                    // t*128 + b
  const ushort* hrow = h_plain + (size_t)wid * HHH + lane * 8;
  uint4 hv = *(const uint4*)hrow;
  float hf[8];
  hf[0] = __uint_as_float(hv.x << 16); hf[1] = __uint_as_float(hv.x & 0xffff0000u);
  hf[2] = __uint_as_float(hv.y << 16); hf[3] = __uint_as_float(hv.y & 0xffff0000u);
  hf[4] = __uint_as_float(hv.z << 16); hf[5] = __uint_as_float(hv.z & 0xffff0000u);
  hf[6] = __uint_as_float(hv.w << 16); hf[7] = __uint_as_float(hv.w & 0xffff0000u);
#pragma unroll
  for (int tg = 0; tg < TT; ++tg) {
    const float* wrow = W_out + (size_t)tg * HHH + lane * 8;
    float4 w0 = *(const float4*)wrow;
    float4 w1 = *(const float4*)(wrow + 4);
    float s = hf[0]*w0.x + hf[1]*w0.y + hf[2]*w0.z + hf[3]*w0.w
            + hf[4]*w1.x + hf[5]*w1.y + hf[6]*w1.z + hf[7]*w1.w;
#pragma unroll
    for (int off = 32; off >= 1; off >>= 1) s += __shfl_xor(s, off);
    if (lane == 0) feats[(size_t)wid * TT + tg] = s + b_out[tg];
  }
}

// ---------------------------------------------------------------- viterbi: one wave per batch
__global__ __launch_bounds__(64)
void viterbi_kernel(const float* __restrict__ feats, const float* __restrict__ trans,
                    float* __restrict__ out) {
  __shared__ float tr[TT * TT];
  __shared__ float abuf2[2][16];
  __shared__ int   bptr[LSEQ][TT];
  __shared__ float finbuf[16];
  int b = blockIdx.x, lane = threadIdx.x;
  for (int i = lane; i < TT * TT; i += 64) tr[i] = trans[i];
  if (lane < 16) abuf2[0][lane] = NEGV;
  __syncthreads();
  if (lane == START_TAG) abuf2[0][lane] = 0.f;
  int cur = 0;
  for (int l = 0; l < LSEQ; ++l) {
    float feat = (lane < TT) ? feats[((size_t)l * NB + b) * TT + lane] : 0.f;
    if (lane < TT) {
      float best = -3.4e38f; int bp = 0;
#pragma unroll
      for (int p = 0; p < TT; ++p) {
        float s2 = abuf2[cur][p] + tr[lane * TT + p];
        if (s2 > best) { best = s2; bp = p; }     // first-max = jnp.argmax
      }
      abuf2[cur ^ 1][lane] = best + feat;
      bptr[l][lane] = bp;
    }
    cur ^= 1;
  }
  if (lane < 16) finbuf[lane] = -3.4e38f;
  if (lane < TT) finbuf[lane] = abuf2[cur][lane] + tr[STOP_TAG * TT + lane];
  if (lane == 0) {
    float bestv = finbuf[0]; int btag = 0;
    for (int p = 1; p < TT; ++p) if (finbuf[p] > bestv) { bestv = finbuf[p]; btag = p; }
    out[b] = bestv;
    float* pathp = out + NB + (size_t)b * LSEQ;
    int tag = btag;
    pathp[LSEQ - 1] = (float)tag;
    for (int l = LSEQ - 1; l >= 1; --l) {
      tag = bptr[l][tag];
      pathp[l - 1] = (float)tag;
    }
  }
}

// ---------------------------------------------------------------- launch
extern "C" void kernel_launch(void* const* d_in, const int* in_sizes, int n_in,
                              void* d_out, int out_size, void* d_ws, size_t ws_size,
                              hipStream_t stream) {
  const int*   tokens = (const int*)d_in[0];
  const float* emb    = (const float*)d_in[1];
  const float* Wih_f  = (const float*)d_in[2];
  const float* Whh_f  = (const float*)d_in[3];
  const float* bih_f  = (const float*)d_in[4];
  const float* bhh_f  = (const float*)d_in[5];
  const float* Wih_b  = (const float*)d_in[6];
  const float* Whh_b  = (const float*)d_in[7];
  const float* bih_b  = (const float*)d_in[8];
  const float* bhh_b  = (const float*)d_in[9];
  const float* W_out  = (const float*)d_in[10];
  const float* b_out  = (const float*)d_in[11];
  const float* trans  = (const float*)d_in[12];
  const float* h0     = (const float*)d_in[13];
  const float* c0     = (const float*)d_in[14];
  float* out = (float*)d_out;

  char* ws = (char*)d_ws;
  uint4* x_frag  = (uint4*)ws;
  uint4* h_frag  = (uint4*)(ws + OFF_HFRAG);
  ushort* h_plain = (ushort*)(ws + OFF_HPLAIN);
  float* feats   = (float*)(ws + OFF_FEATS);
  unsigned int* flags = (unsigned int*)(ws + OFF_FLAGS);

  hipFuncSetAttribute((const void*)lstm_kernel,
                      hipFuncAttributeMaxDynamicSharedMemorySize, LDS_BYTES);

  init_kernel<<<1, 64, 0, stream>>>(flags);
  embed_kernel<<<(LSEQ * 4 * 16 * 64) / 256, 256, 0, stream>>>(tokens, emb, x_frag);
  lstm_kernel<<<64, 256, LDS_BYTES, stream>>>(x_frag, Wih_f, Whh_f, bih_f, bhh_f,
                                              Wih_b, Whh_b, bih_b, bhh_b,
                                              h0, c0, h_frag, h_plain, flags);
  feats_kernel<<<(LSEQ * NB) / 4, 256, 0, stream>>>(h_plain, W_out, b_out, feats);
  viterbi_kernel<<<NB, 64, 0, stream>>>(feats, trans, out);
}